// Round 10
// baseline (192.765 us; speedup 1.0000x reference)
//
#include <hip/hip_runtime.h>
#include <hip/hip_bf16.h>

typedef __attribute__((ext_vector_type(8))) short short8;
typedef __attribute__((ext_vector_type(4))) short s4v;
typedef __attribute__((ext_vector_type(4))) float floatx4;

__device__ inline floatx4 mfma_bf16(short8 a, short8 b, floatx4 c) {
  return __builtin_amdgcn_mfma_f32_16x16x32_bf16(a, b, c, 0, 0, 0);
}
__device__ inline float exp2_fast(float x) { return __builtin_amdgcn_exp2f(x); }

__device__ inline short bf16s(float f) {
  __hip_bfloat16 h = __float2bfloat16(f);
  return *reinterpret_cast<short*>(&h);
}
__device__ inline float sbf16(short s) {
  return __bfloat162float(*reinterpret_cast<__hip_bfloat16*>(&s));
}

// async global->LDS, 16B per lane. LDS dest must be wave-uniform base + lane*16.
__device__ inline void gld16(__hip_bfloat16* lds, const __hip_bfloat16* g) {
  __builtin_amdgcn_global_load_lds(
      (const __attribute__((address_space(1))) void*)g,
      (__attribute__((address_space(3))) void*)lds, 16, 0, 0);
}

// ---------------------------------------------------------------- fused cvt
__global__ __launch_bounds__(256) void cvt_all(
    const float* __restrict__ x, const float* __restrict__ wqkv,
    const float* __restrict__ wout, __hip_bfloat16* __restrict__ xb,
    __hip_bfloat16* __restrict__ wqkvb, __hip_bfloat16* __restrict__ wob) {
  const int n1 = 4194304, n2 = 3145728;  // n3 = 1048576
  int i = (blockIdx.x * 256 + threadIdx.x) * 8;
  const float* src;
  __hip_bfloat16* dst;
  int off;
  if (i < n1) { src = x; dst = xb; off = i; }
  else if (i < n1 + n2) { src = wqkv; dst = wqkvb; off = i - n1; }
  else { src = wout; dst = wob; off = i - n1 - n2; }
  float4 a = *reinterpret_cast<const float4*>(src + off);
  float4 b = *reinterpret_cast<const float4*>(src + off + 4);
  __hip_bfloat16 t[8];
  t[0] = __float2bfloat16(a.x); t[1] = __float2bfloat16(a.y);
  t[2] = __float2bfloat16(a.z); t[3] = __float2bfloat16(a.w);
  t[4] = __float2bfloat16(b.x); t[5] = __float2bfloat16(b.y);
  t[6] = __float2bfloat16(b.z); t[7] = __float2bfloat16(b.w);
  *reinterpret_cast<short8*>(dst + off) = *reinterpret_cast<short8*>(t);
}

// ---------------------------------------------------------------- GEMM 128xTN
template<int TN, bool OUT_BF16>
__global__ __launch_bounds__(256) void gemm_bt(
    const __hip_bfloat16* __restrict__ A, const __hip_bfloat16* __restrict__ Bt,
    const float* __restrict__ bias, void* __restrict__ Cout,
    int M, int N, int K) {
  __shared__ __align__(16) __hip_bfloat16 As[128 * 64];
  __shared__ __align__(16) __hip_bfloat16 Bs[TN * 64];
  const int tid = threadIdx.x;
  const int wave = tid >> 6, lane = tid & 63, quad = lane >> 4, l15 = lane & 15;
  const int wm = (wave >> 1) * 64, wn = (wave & 1) * (TN / 2);
  const int m0 = blockIdx.y * 128, n0 = blockIdx.x * TN;
  const int NC = TN / 32;

  floatx4 acc[4][NC];
  for (int r = 0; r < 4; ++r)
    for (int c = 0; c < NC; ++c) acc[r][c] = (floatx4){0.f, 0.f, 0.f, 0.f};

  for (int k0 = 0; k0 < K; k0 += 64) {
    __syncthreads();
    for (int it = 0; it < 4; ++it) {
      int idx = it * 256 + tid;
      int row = idx >> 3, col = ((idx & 7) ^ (row & 7)) * 8;
      gld16(&As[idx * 8], A + (size_t)(m0 + row) * K + k0 + col);
    }
    for (int it = 0; it < TN * 64 / 2048; ++it) {
      int idx = it * 256 + tid;
      int row = idx >> 3, col = ((idx & 7) ^ (row & 7)) * 8;
      gld16(&Bs[idx * 8], Bt + (size_t)(n0 + row) * K + k0 + col);
    }
    __syncthreads();
    for (int ks = 0; ks < 2; ++ks) {
      short8 af[4], bf[NC];
      for (int r = 0; r < 4; ++r) {
        int row = wm + r * 16 + l15;
        af[r] = *reinterpret_cast<const short8*>(
            &As[row * 64 + (((ks * 4 + quad) ^ (l15 & 7)) * 8)]);
      }
      for (int c = 0; c < NC; ++c) {
        int row = wn + c * 16 + l15;
        bf[c] = *reinterpret_cast<const short8*>(
            &Bs[row * 64 + (((ks * 4 + quad) ^ (l15 & 7)) * 8)]);
      }
      for (int r = 0; r < 4; ++r)
        for (int c = 0; c < NC; ++c)
          acc[r][c] = mfma_bf16(af[r], bf[c], acc[r][c]);
    }
  }

  for (int c = 0; c < NC; ++c) {
    int gn = n0 + wn + c * 16 + l15;
    float bv = bias[gn];
    for (int r = 0; r < 4; ++r)
      for (int rg = 0; rg < 4; ++rg) {
        int gm = m0 + wm + r * 16 + quad * 4 + rg;
        float v = acc[r][c][rg] + bv;
        if (OUT_BF16)
          ((__hip_bfloat16*)Cout)[(size_t)gm * N + gn] = __float2bfloat16(v);
        else
          ((float*)Cout)[(size_t)gm * N + gn] = v;
      }
  }
}

// ---------------------------------------------------------------- flash attn v9
// Single-barrier pipeline: window W_j = [issue K-DMA_{j+1} + V-reg-load_{j+1},
// PV_{j-1}, QK_j, exp2/P-write_j, V-commit_j, barrier]. All cross-wave hazards
// are barrier-separated or parity-separated (P/K/V all double-buffered).
// k-sliced QK, d-sliced PV, m=0 softmax. LDS 48KB -> 3 blocks/CU.
__global__ __launch_bounds__(256, 3) void flash_attn(
    const __hip_bfloat16* __restrict__ qkv, __hip_bfloat16* __restrict__ out) {
  const int S = 2048, QKV = 3072;
  const int bx = blockIdx.x;
  const int g = (blockIdx.y >> 3) + 2 * blockIdx.z;
  int qt;
  if (g == 0)      qt = bx;
  else if (g == 1) qt = 31 - bx;
  else if (g == 2) qt = (bx + 8) & 31;
  else             qt = (23 - bx) & 31;
  const int h = blockIdx.y, b = blockIdx.z;
  const int q0 = qt * 64;
  __shared__ __align__(16) short Ps[2][64 * 64];   // [tile parity]; Ps[1] stages Q
  __shared__ __align__(16) short Ks[2][64 * 64];   // col-block swizzled
  __shared__ __align__(16) short Vts[2][64 * 64];  // V^T, j-block swizzled
  const int tid = threadIdx.x;
  const int wave = tid >> 6, lane = tid & 63, quad = lane >> 4, l15 = lane & 15;
  const int rx = l15 & 7;
  const __hip_bfloat16* base = qkv + (size_t)b * S * QKV;
  const float c2 = 0.18033688011112042f;  // (1/sqrt(64)) * log2(e)
  const floatx4 zero4 = {0.f, 0.f, 0.f, 0.f};
  const int j4 = (tid >> 4) * 4, d4 = (tid & 15) * 4;  // V patch coords

  // ---- prologue: Q (scaled) -> Ps[1]; K tile0 DMA; V tile0 -> regs
  for (int it = 0; it < 2; ++it) {
    int v = tid + it * 256;
    int row = v >> 3, cb = v & 7;
    int colp = (cb ^ (row & 7)) * 8;
    gld16((__hip_bfloat16*)&Ks[0][v * 8],
          base + (size_t)row * QKV + 1024 + h * 64 + colp);
    short8 qv = *reinterpret_cast<const short8*>(
        base + (size_t)(q0 + row) * QKV + h * 64 + cb * 8);
    short qs[8];
    for (int e = 0; e < 8; ++e) qs[e] = bf16s(sbf16(qv[e]) * c2);
    *reinterpret_cast<short8*>(&Ps[1][row * 64 + colp]) = *reinterpret_cast<short8*>(qs);
  }
  s4v vr[4];
  for (int jj = 0; jj < 4; ++jj)
    vr[jj] = *reinterpret_cast<const s4v*>(
        base + (size_t)(j4 + jj) * QKV + 2048 + h * 64 + d4);
  __syncthreads();  // barrier_{-1}: Q visible, K0 DMA drained

  short8 aq[4][2];
  for (int t4 = 0; t4 < 4; ++t4)
    for (int s = 0; s < 2; ++s)
      aq[t4][s] = *reinterpret_cast<const short8*>(
          &Ps[1][(t4 * 16 + l15) * 64 + (((s * 4 + quad) ^ rx) * 8)]);

  floatx4 o_acc[4];
  for (int m = 0; m < 4; ++m) o_acc[m] = zero4;
  float lsum4[4] = {0.f, 0.f, 0.f, 0.f};
  const int krow = 16 * wave + l15;   // wave's K slice row / d column
  const int dswz = (krow & 7) ^ ((krow >> 3) & 7);

  for (int j = 0; j <= qt; ++j) {
    const int cj = j & 1, pj = cj ^ 1;

    // ---- issue next tile's K DMA + V register loads (longest latency first)
    s4v vrn[4];
    if (j < qt) {
      const size_t r1 = (size_t)(j + 1) * 64;
      for (int it = 0; it < 2; ++it) {
        int v = tid + it * 256;
        int row = v >> 3, cb = v & 7;
        int colp = (cb ^ (row & 7)) * 8;
        gld16((__hip_bfloat16*)&Ks[pj][v * 8],
              base + (r1 + row) * QKV + 1024 + h * 64 + colp);
      }
      for (int jj = 0; jj < 4; ++jj)
        vrn[jj] = *reinterpret_cast<const s4v*>(
            base + (r1 + j4 + jj) * QKV + 2048 + h * 64 + d4);
    }

    // ---- PV_{j-1}: all 64 q x wave's 16 d (buffers parity pj)
    if (j > 0) {
      for (int s = 0; s < 2; ++s) {
        short8 bv = *reinterpret_cast<const short8*>(
            &Vts[pj][krow * 64 + (((4 * s + quad) ^ dswz) * 8)]);
        for (int m = 0; m < 4; ++m) {
          short8 ap = *reinterpret_cast<const short8*>(
              &Ps[pj][(m * 16 + l15) * 64 + (((4 * s + quad) ^ rx) * 8)]);
          o_acc[m] = mfma_bf16(ap, bv, o_acc[m]);
        }
      }
    }

    // ---- QK_j: wave's 16 k-rows x all 64 q (K parity cj)
    short8 ak0 = *reinterpret_cast<const short8*>(
        &Ks[cj][krow * 64 + ((quad ^ rx) * 8)]);
    short8 ak1 = *reinterpret_cast<const short8*>(
        &Ks[cj][krow * 64 + (((4 + quad) ^ rx) * 8)]);
    floatx4 sc[4];
    for (int t4 = 0; t4 < 4; ++t4) {
      sc[t4] = mfma_bf16(ak0, aq[t4][0], zero4);
      sc[t4] = mfma_bf16(ak1, aq[t4][1], sc[t4]);
    }
    if (j == qt) {  // diagonal mask (local coords)
      int kloc = 16 * wave + quad * 4;
      for (int t4 = 0; t4 < 4; ++t4)
        for (int rg = 0; rg < 4; ++rg)
          if (kloc + rg > t4 * 16 + l15) sc[t4][rg] = -1e30f;
    }

    // ---- exp2 (m=0) + P-write_j (parity cj)
    const int pcol = ((2 * wave + (quad >> 1)) ^ rx) * 8 + (quad & 1) * 4;
    for (int t4 = 0; t4 < 4; ++t4) {
      short pp[4];
      for (int rg = 0; rg < 4; ++rg) {
        float p = exp2_fast(sc[t4][rg]);
        lsum4[t4] += p;
        pp[rg] = bf16s(p);
      }
      *reinterpret_cast<s4v*>(&Ps[cj][(t4 * 16 + l15) * 64 + pcol]) =
          *reinterpret_cast<s4v*>(pp);
    }

    // ---- V-commit_j (parity cj) from regs loaded last window
    for (int e = 0; e < 4; ++e) {
      int d = d4 + e;
      int pb = (j4 >> 3) ^ (d & 7) ^ ((d >> 3) & 7);
      s4v w4 = {vr[0][e], vr[1][e], vr[2][e], vr[3][e]};
      *reinterpret_cast<s4v*>(&Vts[cj][d * 64 + pb * 8 + (j4 & 7)]) = w4;
    }
    for (int jj = 0; jj < 4; ++jj) vr[jj] = vrn[jj];

    __syncthreads();  // the single per-iter barrier
  }

  // ---- epilogue: PV_qt (parity pq), then lsum merge in the other P buffer
  const int pq = qt & 1;
  for (int s = 0; s < 2; ++s) {
    short8 bv = *reinterpret_cast<const short8*>(
        &Vts[pq][krow * 64 + (((4 * s + quad) ^ dswz) * 8)]);
    for (int m = 0; m < 4; ++m) {
      short8 ap = *reinterpret_cast<const short8*>(
          &Ps[pq][(m * 16 + l15) * 64 + (((4 * s + quad) ^ rx) * 8)]);
      o_acc[m] = mfma_bf16(ap, bv, o_acc[m]);
    }
  }
  for (int t4 = 0; t4 < 4; ++t4) {
    lsum4[t4] += __shfl_xor(lsum4[t4], 16);
    lsum4[t4] += __shfl_xor(lsum4[t4], 32);
  }
  float* Lf = (float*)&Ps[pq ^ 1][0];  // not read by any wave's PV_qt
  if (quad == 0)
    for (int t4 = 0; t4 < 4; ++t4)
      Lf[wave * 64 + t4 * 16 + l15] = lsum4[t4];
  __syncthreads();
  if (tid < 64)
    Lf[256 + tid] = 1.0f / (Lf[tid] + Lf[64 + tid] + Lf[128 + tid] + Lf[192 + tid]);
  __syncthreads();

  const int dcol = h * 64 + krow;
  for (int m = 0; m < 4; ++m)
    for (int rg = 0; rg < 4; ++rg) {
      int q = m * 16 + quad * 4 + rg;
      out[(size_t)(b * S + q0 + q) * 1024 + dcol] =
          __float2bfloat16(o_acc[m][rg] * Lf[256 + q]);
    }
}

// ---------------------------------------------------------------- launch
extern "C" void kernel_launch(void* const* d_in, const int* in_sizes, int n_in,
                              void* d_out, int out_size, void* d_ws, size_t ws_size,
                              hipStream_t stream) {
  const float* x    = (const float*)d_in[0];
  const float* Wqkv = (const float*)d_in[1];
  const float* bqkv = (const float*)d_in[2];
  const float* Wout = (const float*)d_in[3];
  const float* bout = (const float*)d_in[4];
  float* out = (float*)d_out;

  const int BS = 2 * 2048;
  const int D = 1024;
  char* ws = (char*)d_ws;
  __hip_bfloat16* xb    = (__hip_bfloat16*)(ws);
  __hip_bfloat16* wqkvb = (__hip_bfloat16*)(ws + (size_t)8  * 1048576);
  __hip_bfloat16* wob   = (__hip_bfloat16*)(ws + (size_t)14 * 1048576);
  __hip_bfloat16* qkvb  = (__hip_bfloat16*)(ws + (size_t)16 * 1048576);
  __hip_bfloat16* attnb = (__hip_bfloat16*)(ws + (size_t)40 * 1048576);

  cvt_all<<<4096, 256, 0, stream>>>(x, Wqkv, Wout, xb, wqkvb, wob);

  gemm_bt<128, true><<<dim3(3072 / 128, BS / 128), 256, 0, stream>>>(
      xb, wqkvb, bqkv, qkvb, BS, 3 * D, D);

  flash_attn<<<dim3(32, 16, 2), 256, 0, stream>>>(qkvb, attnb);

  gemm_bt<64, false><<<dim3(1024 / 64, BS / 128), 256, 0, stream>>>(
      attnb, wob, bout, out, BS, D, D);
}

// Round 11
// 182.077 us; speedup vs baseline: 1.0587x; 1.0587x over previous
//
#include <hip/hip_runtime.h>
#include <hip/hip_bf16.h>

typedef __attribute__((ext_vector_type(8))) short short8;
typedef __attribute__((ext_vector_type(4))) short s4v;
typedef __attribute__((ext_vector_type(4))) float floatx4;

__device__ inline floatx4 mfma_bf16(short8 a, short8 b, floatx4 c) {
  return __builtin_amdgcn_mfma_f32_16x16x32_bf16(a, b, c, 0, 0, 0);
}
__device__ inline float exp2_fast(float x) { return __builtin_amdgcn_exp2f(x); }

__device__ inline short bf16s(float f) {
  __hip_bfloat16 h = __float2bfloat16(f);
  return *reinterpret_cast<short*>(&h);
}
__device__ inline float sbf16(short s) {
  return __bfloat162float(*reinterpret_cast<__hip_bfloat16*>(&s));
}

// async global->LDS, 16B per lane. LDS dest must be wave-uniform base + lane*16.
__device__ inline void gld16(__hip_bfloat16* lds, const __hip_bfloat16* g) {
  __builtin_amdgcn_global_load_lds(
      (const __attribute__((address_space(1))) void*)g,
      (__attribute__((address_space(3))) void*)lds, 16, 0, 0);
}

// ---------------------------------------------------------------- fused cvt
__global__ __launch_bounds__(256) void cvt_all(
    const float* __restrict__ x, const float* __restrict__ wqkv,
    const float* __restrict__ wout, __hip_bfloat16* __restrict__ xb,
    __hip_bfloat16* __restrict__ wqkvb, __hip_bfloat16* __restrict__ wob) {
  const int n1 = 4194304, n2 = 3145728;  // n3 = 1048576
  int i = (blockIdx.x * 256 + threadIdx.x) * 8;
  const float* src;
  __hip_bfloat16* dst;
  int off;
  if (i < n1) { src = x; dst = xb; off = i; }
  else if (i < n1 + n2) { src = wqkv; dst = wqkvb; off = i - n1; }
  else { src = wout; dst = wob; off = i - n1 - n2; }
  float4 a = *reinterpret_cast<const float4*>(src + off);
  float4 b = *reinterpret_cast<const float4*>(src + off + 4);
  __hip_bfloat16 t[8];
  t[0] = __float2bfloat16(a.x); t[1] = __float2bfloat16(a.y);
  t[2] = __float2bfloat16(a.z); t[3] = __float2bfloat16(a.w);
  t[4] = __float2bfloat16(b.x); t[5] = __float2bfloat16(b.y);
  t[6] = __float2bfloat16(b.z); t[7] = __float2bfloat16(b.w);
  *reinterpret_cast<short8*>(dst + off) = *reinterpret_cast<short8*>(t);
}

// ---------------------------------------------------------------- GEMM 128xTN
template<int TN, bool OUT_BF16>
__global__ __launch_bounds__(256) void gemm_bt(
    const __hip_bfloat16* __restrict__ A, const __hip_bfloat16* __restrict__ Bt,
    const float* __restrict__ bias, void* __restrict__ Cout,
    int M, int N, int K) {
  __shared__ __align__(16) __hip_bfloat16 As[128 * 64];
  __shared__ __align__(16) __hip_bfloat16 Bs[TN * 64];
  const int tid = threadIdx.x;
  const int wave = tid >> 6, lane = tid & 63, quad = lane >> 4, l15 = lane & 15;
  const int wm = (wave >> 1) * 64, wn = (wave & 1) * (TN / 2);
  const int m0 = blockIdx.y * 128, n0 = blockIdx.x * TN;
  const int NC = TN / 32;

  floatx4 acc[4][NC];
  for (int r = 0; r < 4; ++r)
    for (int c = 0; c < NC; ++c) acc[r][c] = (floatx4){0.f, 0.f, 0.f, 0.f};

  for (int k0 = 0; k0 < K; k0 += 64) {
    __syncthreads();
    for (int it = 0; it < 4; ++it) {
      int idx = it * 256 + tid;
      int row = idx >> 3, col = ((idx & 7) ^ (row & 7)) * 8;
      gld16(&As[idx * 8], A + (size_t)(m0 + row) * K + k0 + col);
    }
    for (int it = 0; it < TN * 64 / 2048; ++it) {
      int idx = it * 256 + tid;
      int row = idx >> 3, col = ((idx & 7) ^ (row & 7)) * 8;
      gld16(&Bs[idx * 8], Bt + (size_t)(n0 + row) * K + k0 + col);
    }
    __syncthreads();
    for (int ks = 0; ks < 2; ++ks) {
      short8 af[4], bf[NC];
      for (int r = 0; r < 4; ++r) {
        int row = wm + r * 16 + l15;
        af[r] = *reinterpret_cast<const short8*>(
            &As[row * 64 + (((ks * 4 + quad) ^ (l15 & 7)) * 8)]);
      }
      for (int c = 0; c < NC; ++c) {
        int row = wn + c * 16 + l15;
        bf[c] = *reinterpret_cast<const short8*>(
            &Bs[row * 64 + (((ks * 4 + quad) ^ (l15 & 7)) * 8)]);
      }
      for (int r = 0; r < 4; ++r)
        for (int c = 0; c < NC; ++c)
          acc[r][c] = mfma_bf16(af[r], bf[c], acc[r][c]);
    }
  }

  for (int c = 0; c < NC; ++c) {
    int gn = n0 + wn + c * 16 + l15;
    float bv = bias[gn];
    for (int r = 0; r < 4; ++r)
      for (int rg = 0; rg < 4; ++rg) {
        int gm = m0 + wm + r * 16 + quad * 4 + rg;
        float v = acc[r][c][rg] + bv;
        if (OUT_BF16)
          ((__hip_bfloat16*)Cout)[(size_t)gm * N + gn] = __float2bfloat16(v);
        else
          ((float*)Cout)[(size_t)gm * N + gn] = v;
      }
  }
}

// ---------------------------------------------------------------- flash attn v10
// LDS-minimal: K and V are wave-private under the k-sliced/d-sliced split, so
// both load DIRECTLY global->registers (K: 2 dwordx4 A-frags; V: 16 scalar
// bf16 B-frag gathers, issued one window ahead). Only P round-trips LDS
// (double-buffered, 16KB total). One barrier/iter, lgkmcnt-only drain
// (no global_load_lds in the loop). m=0 softmax; balance-mapped qt.
__global__ __launch_bounds__(256, 4) void flash_attn(
    const __hip_bfloat16* __restrict__ qkv, __hip_bfloat16* __restrict__ out) {
  const int S = 2048, QKV = 3072;
  const int bx = blockIdx.x;
  const int g = (blockIdx.y >> 3) + 2 * blockIdx.z;
  int qt;
  if (g == 0)      qt = bx;
  else if (g == 1) qt = 31 - bx;
  else if (g == 2) qt = (bx + 8) & 31;
  else             qt = (23 - bx) & 31;
  const int h = blockIdx.y, b = blockIdx.z;
  const int q0 = qt * 64;
  __shared__ __align__(16) short Ps[2][64 * 64];  // P double-buffer; Ps[1] stages Q
  const int tid = threadIdx.x;
  const int wave = tid >> 6, lane = tid & 63, quad = lane >> 4, l15 = lane & 15;
  const int rx = l15 & 7;
  const __hip_bfloat16* base = qkv + (size_t)b * S * QKV;
  const float c2 = 0.18033688011112042f;  // (1/sqrt(64)) * log2(e)
  const floatx4 zero4 = {0.f, 0.f, 0.f, 0.f};
  const int krow = 16 * wave + l15;  // wave's K-row (QK) and d-column (PV)

  const __hip_bfloat16* kbase = base + 1024 + h * 64;  // K plane
  const __hip_bfloat16* vbase = base + 2048 + h * 64;  // V plane

  // ---- prologue: Q (scaled) -> Ps[1]; K_0 frags -> regs
  for (int it = 0; it < 2; ++it) {
    int v = tid + it * 256;
    int row = v >> 3, cb = v & 7;
    int colp = (cb ^ (row & 7)) * 8;
    short8 qv = *reinterpret_cast<const short8*>(
        base + (size_t)(q0 + row) * QKV + h * 64 + cb * 8);
    short qs[8];
    for (int e = 0; e < 8; ++e) qs[e] = bf16s(sbf16(qv[e]) * c2);
    *reinterpret_cast<short8*>(&Ps[1][row * 64 + colp]) = *reinterpret_cast<short8*>(qs);
  }
  short8 kA0 = *reinterpret_cast<const short8*>(
      kbase + (size_t)krow * QKV + quad * 8);
  short8 kA1 = *reinterpret_cast<const short8*>(
      kbase + (size_t)krow * QKV + 32 + quad * 8);
  __syncthreads();  // Q visible

  short8 aq[4][2];  // Q B-frags: all 64 q rows x both d-halves
  for (int t4 = 0; t4 < 4; ++t4)
    for (int s = 0; s < 2; ++s)
      aq[t4][s] = *reinterpret_cast<const short8*>(
          &Ps[1][(t4 * 16 + l15) * 64 + (((s * 4 + quad) ^ rx) * 8)]);
  // (safe: Ps[1] is first overwritten as P in window j=1, after barrier_0)

  floatx4 o_acc[4];
  for (int m = 0; m < 4; ++m) o_acc[m] = zero4;
  float lsum4[4] = {0.f, 0.f, 0.f, 0.f};
  short8 vA0, vA1;  // V_{j-1} B-frags

  for (int j = 0; j <= qt; ++j) {
    const int cj = j & 1, pj = cj ^ 1;

    // ---- issue K_{j+1} A-frags and V_j B-frags (consumed next window)
    short8 kB0, kB1, vB0, vB1;
    if (j < qt) {
      const __hip_bfloat16* kp = kbase + (size_t)((j + 1) * 64 + krow) * QKV;
      kB0 = *reinterpret_cast<const short8*>(kp + quad * 8);
      kB1 = *reinterpret_cast<const short8*>(kp + 32 + quad * 8);
    }
    {
      const __hip_bfloat16* vp = vbase + (size_t)(j * 64 + quad * 8) * QKV + krow;
      for (int i = 0; i < 8; ++i) {
        vB0[i] = *reinterpret_cast<const short*>(vp + (size_t)i * QKV);
        vB1[i] = *reinterpret_cast<const short*>(vp + (size_t)(32 + i) * QKV);
      }
    }

    // ---- PV_{j-1}: all 64 q x wave's 16 d (P parity pj, V regs)
    if (j > 0) {
      for (int s = 0; s < 2; ++s) {
        short8 bv = s ? vA1 : vA0;
        for (int m = 0; m < 4; ++m) {
          short8 ap = *reinterpret_cast<const short8*>(
              &Ps[pj][(m * 16 + l15) * 64 + (((4 * s + quad) ^ rx) * 8)]);
          o_acc[m] = mfma_bf16(ap, bv, o_acc[m]);
        }
      }
    }

    // ---- QK_j: wave's 16 k-rows x all 64 q (K regs)
    floatx4 sc[4];
    for (int t4 = 0; t4 < 4; ++t4) {
      sc[t4] = mfma_bf16(kA0, aq[t4][0], zero4);
      sc[t4] = mfma_bf16(kA1, aq[t4][1], sc[t4]);
    }
    if (j == qt) {  // diagonal mask (local coords)
      int kloc = 16 * wave + quad * 4;
      for (int t4 = 0; t4 < 4; ++t4)
        for (int rg = 0; rg < 4; ++rg)
          if (kloc + rg > t4 * 16 + l15) sc[t4][rg] = -1e30f;
    }

    // ---- exp2 (m=0) + P-write_j (parity cj)
    const int pcol = ((2 * wave + (quad >> 1)) ^ rx) * 8 + (quad & 1) * 4;
    for (int t4 = 0; t4 < 4; ++t4) {
      short pp[4];
      for (int rg = 0; rg < 4; ++rg) {
        float p = exp2_fast(sc[t4][rg]);
        lsum4[t4] += p;
        pp[rg] = bf16s(p);
      }
      *reinterpret_cast<s4v*>(&Ps[cj][(t4 * 16 + l15) * 64 + pcol]) =
          *reinterpret_cast<s4v*>(pp);
    }

    kA0 = kB0; kA1 = kB1; vA0 = vB0; vA1 = vB1;
    __syncthreads();  // single barrier: P_j visible, PV_{j-1} reads done
  }

  // ---- epilogue: PV_qt (V_qt regs, P parity qt&1)
  const int pq = qt & 1;
  for (int s = 0; s < 2; ++s) {
    short8 bv = s ? vA1 : vA0;
    for (int m = 0; m < 4; ++m) {
      short8 ap = *reinterpret_cast<const short8*>(
          &Ps[pq][(m * 16 + l15) * 64 + (((4 * s + quad) ^ rx) * 8)]);
      o_acc[m] = mfma_bf16(ap, bv, o_acc[m]);
    }
  }
  // lsum merge (additive, m=0): quad-reduce then LDS table in the other buffer
  for (int t4 = 0; t4 < 4; ++t4) {
    lsum4[t4] += __shfl_xor(lsum4[t4], 16);
    lsum4[t4] += __shfl_xor(lsum4[t4], 32);
  }
  float* Lf = (float*)&Ps[pq ^ 1][0];  // disjoint from PV_qt reads
  if (quad == 0)
    for (int t4 = 0; t4 < 4; ++t4)
      Lf[wave * 64 + t4 * 16 + l15] = lsum4[t4];
  __syncthreads();
  if (tid < 64)
    Lf[256 + tid] = 1.0f / (Lf[tid] + Lf[64 + tid] + Lf[128 + tid] + Lf[192 + tid]);
  __syncthreads();

  const int dcol = h * 64 + krow;
  for (int m = 0; m < 4; ++m)
    for (int rg = 0; rg < 4; ++rg) {
      int q = m * 16 + quad * 4 + rg;
      out[(size_t)(b * S + q0 + q) * 1024 + dcol] =
          __float2bfloat16(o_acc[m][rg] * Lf[256 + q]);
    }
}

// ---------------------------------------------------------------- launch
extern "C" void kernel_launch(void* const* d_in, const int* in_sizes, int n_in,
                              void* d_out, int out_size, void* d_ws, size_t ws_size,
                              hipStream_t stream) {
  const float* x    = (const float*)d_in[0];
  const float* Wqkv = (const float*)d_in[1];
  const float* bqkv = (const float*)d_in[2];
  const float* Wout = (const float*)d_in[3];
  const float* bout = (const float*)d_in[4];
  float* out = (float*)d_out;

  const int BS = 2 * 2048;
  const int D = 1024;
  char* ws = (char*)d_ws;
  __hip_bfloat16* xb    = (__hip_bfloat16*)(ws);
  __hip_bfloat16* wqkvb = (__hip_bfloat16*)(ws + (size_t)8  * 1048576);
  __hip_bfloat16* wob   = (__hip_bfloat16*)(ws + (size_t)14 * 1048576);
  __hip_bfloat16* qkvb  = (__hip_bfloat16*)(ws + (size_t)16 * 1048576);
  __hip_bfloat16* attnb = (__hip_bfloat16*)(ws + (size_t)40 * 1048576);

  cvt_all<<<4096, 256, 0, stream>>>(x, Wqkv, Wout, xb, wqkvb, wob);

  gemm_bt<128, true><<<dim3(3072 / 128, BS / 128), 256, 0, stream>>>(
      xb, wqkvb, bqkv, qkvb, BS, 3 * D, D);

  flash_attn<<<dim3(32, 16, 2), 256, 0, stream>>>(qkvb, attnb);

  gemm_bt<64, false><<<dim3(1024 / 64, BS / 128), 256, 0, stream>>>(
      attnb, wob, bout, out, BS, D, D);
}